// Round 15
// baseline (585.829 us; speedup 1.0000x reference)
//
#include <hip/hip_runtime.h>

// LLM block: B=2,S=2048,D=2048,H=16,KVH=8,HD=128,FF=5504, f32 in/out, bf16 MFMA compute.
// Workspace lifetime note (r13 lesson): wdown @ ws+0 spans 22.5MB and OVERLAPS hbuf
// [16.7MB,22.5MB) -> wd MUST be converted AFTER gateup GEMM (hbuf's last consumer).
#define DM 2048
#define SEQ 2048
#define HD 128
#define FF_ 5504
#define QK_SCALE_L2E 0.12751744f   // 1/sqrt(128) * log2(e); attn softmax in exp2 domain

typedef __bf16 bf16x8 __attribute__((ext_vector_type(8)));
typedef float f32x4 __attribute__((ext_vector_type(4)));
typedef float f32x16 __attribute__((ext_vector_type(16)));
typedef unsigned short u16x8 __attribute__((ext_vector_type(8)));
typedef unsigned int u32x4 __attribute__((ext_vector_type(4)));

typedef __attribute__((address_space(1))) void* gas1;
typedef __attribute__((address_space(3))) void* las3;
#define GLDS16(g, s) __builtin_amdgcn_global_load_lds((gas1)(g), (las3)(s), 16, 0, 0)

static __device__ __forceinline__ float bf2f(unsigned short u) {
  union { unsigned int i; float f; } c; c.i = ((unsigned int)u) << 16; return c.f;
}
static __device__ __forceinline__ unsigned short f2bf(float f) {
  __bf16 b = (__bf16)f;
  return __builtin_bit_cast(unsigned short, b);
}
static __device__ __forceinline__ unsigned int pk2(float a, float b) {
  return (unsigned int)f2bf(a) | ((unsigned int)f2bf(b) << 16);
}
static __device__ __forceinline__ float fexp2(float x) { return exp2f(x); }
static __device__ __forceinline__ float max3f(float a, float b, float c) {
  return fmaxf(fmaxf(a, b), c);   // clang fuses to v_max3_f32 (T17)
}

// -------- merged prep: f32->bf16 convert (wq|wk|wv|wo) + RMSNorm(x,g1) --------------
__global__ __launch_bounds__(256) void k_prep(const float* __restrict__ wq,
                                              const float* __restrict__ wk,
                                              const float* __restrict__ wv,
                                              const float* __restrict__ wo,
                                              unsigned short* __restrict__ wqkv,
                                              unsigned short* __restrict__ wo_bf,
                                              const float* __restrict__ x,
                                              const float* __restrict__ g1,
                                              unsigned short* __restrict__ hbuf) {
  int b = blockIdx.x, tid = threadIdx.x;
  if (b < 6144) {   // weight convert, 1 row/block
    const float* src;
    unsigned short* dst;
    if (b < 2048)      { src = wq + (size_t)b * DM;          dst = wqkv + (size_t)b * DM; }
    else if (b < 3072) { src = wk + (size_t)(b - 2048) * DM; dst = wqkv + 4194304 + (size_t)(b - 2048) * DM; }
    else if (b < 4096) { src = wv + (size_t)(b - 3072) * DM; dst = wqkv + 6291456 + (size_t)(b - 3072) * DM; }
    else               { src = wo + (size_t)(b - 4096) * DM; dst = wo_bf + (size_t)(b - 4096) * DM; }
    int i = tid * 8;
    float4 a = *(const float4*)&src[i];
    float4 c = *(const float4*)&src[i + 4];
    u16x8 o;
    o[0] = f2bf(a.x); o[1] = f2bf(a.y); o[2] = f2bf(a.z); o[3] = f2bf(a.w);
    o[4] = f2bf(c.x); o[5] = f2bf(c.y); o[6] = f2bf(c.z); o[7] = f2bf(c.w);
    *(u16x8*)&dst[i] = o;
  } else {          // rmsnorm, 1 row/block
    int row = b - 6144;
    const float* xr = x + (size_t)row * DM;
    float4 a = *(const float4*)&xr[tid * 8];
    float4 c = *(const float4*)&xr[tid * 8 + 4];
    float ss = a.x * a.x + a.y * a.y + a.z * a.z + a.w * a.w +
               c.x * c.x + c.y * c.y + c.z * c.z + c.w * c.w;
#pragma unroll
    for (int off = 32; off > 0; off >>= 1) ss += __shfl_xor(ss, off, 64);
    __shared__ float red[4];
    if ((tid & 63) == 0) red[tid >> 6] = ss;
    __syncthreads();
    float rs = rsqrtf((red[0] + red[1] + red[2] + red[3]) * (1.0f / DM) + 1e-5f);
    float4 ga = *(const float4*)&g1[tid * 8];
    float4 gb = *(const float4*)&g1[tid * 8 + 4];
    u16x8 o;
    o[0] = f2bf(a.x * rs * ga.x); o[1] = f2bf(a.y * rs * ga.y);
    o[2] = f2bf(a.z * rs * ga.z); o[3] = f2bf(a.w * rs * ga.w);
    o[4] = f2bf(c.x * rs * gb.x); o[5] = f2bf(c.y * rs * gb.y);
    o[6] = f2bf(c.z * rs * gb.z); o[7] = f2bf(c.w * rs * gb.w);
    *(u16x8*)&hbuf[(size_t)row * DM + tid * 8] = o;
  }
}

// ---- gate/up interleaved convert: dst row r of group t: r<128 -> wg, else wu ----
__global__ __launch_bounds__(256) void k_conv_gu(const float* __restrict__ g,
                                                 const float* __restrict__ u,
                                                 unsigned short* __restrict__ dst) {
  int i = blockIdx.x * 256 + threadIdx.x;
  int row = i >> 8;
  int c8 = (i & 255) * 8;
  int t = row >> 8, r = row & 255;
  const float* src = (r < 128) ? (g + (size_t)(t * 128 + r) * DM + c8)
                               : (u + (size_t)(t * 128 + (r - 128)) * DM + c8);
  float4 a = *(const float4*)src;
  float4 b = *(const float4*)(src + 4);
  u16x8 o;
  o[0] = f2bf(a.x); o[1] = f2bf(a.y); o[2] = f2bf(a.z); o[3] = f2bf(a.w);
  o[4] = f2bf(b.x); o[5] = f2bf(b.y); o[6] = f2bf(b.z); o[7] = f2bf(b.w);
  *(u16x8*)&dst[(size_t)row * DM + c8] = o;
}

// ---------------- plain convert (wd — MUST run after gateup GEMM, see top note) ------
__global__ __launch_bounds__(256) void k_conv(const float* __restrict__ src,
                                              unsigned short* __restrict__ dst) {
  size_t i = (size_t)(blockIdx.x * 256 + threadIdx.x) * 8;
  float4 a = *(const float4*)&src[i];
  float4 b = *(const float4*)&src[i + 4];
  u16x8 o;
  o[0] = f2bf(a.x); o[1] = f2bf(a.y); o[2] = f2bf(a.z); o[3] = f2bf(a.w);
  o[4] = f2bf(b.x); o[5] = f2bf(b.y); o[6] = f2bf(b.z); o[7] = f2bf(b.w);
  *(u16x8*)&dst[i] = o;
}

// ---------------- RMSNorm (x1, g2): one block per row ----------------
__global__ __launch_bounds__(256) void k_rmsnorm(const float* __restrict__ x,
                                                 const float* __restrict__ g,
                                                 unsigned short* __restrict__ out) {
  int row = blockIdx.x, tid = threadIdx.x;
  const float* xr = x + (size_t)row * DM;
  float4 a = *(const float4*)&xr[tid * 8];
  float4 b = *(const float4*)&xr[tid * 8 + 4];
  float ss = a.x * a.x + a.y * a.y + a.z * a.z + a.w * a.w +
             b.x * b.x + b.y * b.y + b.z * b.z + b.w * b.w;
#pragma unroll
  for (int off = 32; off > 0; off >>= 1) ss += __shfl_xor(ss, off, 64);
  __shared__ float red[4];
  if ((tid & 63) == 0) red[tid >> 6] = ss;
  __syncthreads();
  float rs = rsqrtf((red[0] + red[1] + red[2] + red[3]) * (1.0f / DM) + 1e-5f);
  float4 ga = *(const float4*)&g[tid * 8];
  float4 gb = *(const float4*)&g[tid * 8 + 4];
  u16x8 o;
  o[0] = f2bf(a.x * rs * ga.x); o[1] = f2bf(a.y * rs * ga.y);
  o[2] = f2bf(a.z * rs * ga.z); o[3] = f2bf(a.w * rs * ga.w);
  o[4] = f2bf(b.x * rs * gb.x); o[5] = f2bf(b.y * rs * gb.y);
  o[6] = f2bf(b.z * rs * gb.z); o[7] = f2bf(b.w * rs * gb.w);
  *(u16x8*)&out[(size_t)row * DM + tid * 8] = o;
}

// ============ counted-lgkm pipelined GEMM (r11-r15): C[M,N] = A[M,K]*Bt[N,K]^T ========
// BM=256, BK=64, 512 thr (8 waves 2Mx4N), 2-K-tile LDS dbuf, identity bid->tile.
// r15 (BN=256): ALL 24 ds_reads issued in Q1 (aLO,bLO,bHI,aHI; separate ahi regs,
// +32 VGPR, occupancy unchanged — LDS-bound). Counted lgkm(12)/lgkm(8)/lgkm(0) at
// Q1/Q2/Q3 -> Q3's read-drain eliminated. A1(kt) publish (Q4(kt-1) vmcnt(6)+BAR)
// already precedes Q1(kt) per r11 ledger -> early aHI read is timing-legal.
// lgkm counts ds_reads only (GLDS -> vmcnt). Sync/stage/vmcnt placement unchanged.
// Swizzle: 16B-granule ^= (row&7); source pre-swizzled (rule #21).
// EPI: 0 bf16; 1 f32 res-add; 2 gateup-silu; 3 qkv+fused RoPE.
template <int BN, int EPI>
__global__ __launch_bounds__(512, 1) void k_gemm8p(
    const unsigned short* __restrict__ A, const unsigned short* __restrict__ Bt,
    unsigned short* __restrict__ outB, float* __restrict__ outF,
    const float* __restrict__ res, int N, int K,
    const float* __restrict__ cosT, const float* __restrict__ sinT) {
  constexpr int NF = BN / 64;
  constexpr int BUFSZ = (BN == 256) ? 65536 : 49152;
  __shared__ __attribute__((aligned(16))) unsigned char smem[2][BUFSZ];
  const int tid = threadIdx.x, w = tid >> 6, l = tid & 63;
  const int wr = w >> 2, wc = w & 3, lr = l & 15, lg = l >> 4;
  const int bswz = blockIdx.x;
  const int mt = bswz & 15, nt = bswz >> 4;
  const int m0 = mt * 256, n0 = nt * BN;
  const int nkt = K >> 6;

  const int rA0 = tid >> 3;
  const int rB0 = (BN == 256) ? (((tid >> 8) << 6) + ((tid >> 3) & 31)) : (tid >> 3);
  const int sc = ((tid & 7) ^ ((tid >> 3) & 7)) * 8;
  const unsigned short* Abase = A + (size_t)(m0 + rA0) * K + sc;
  const unsigned short* Bbase = Bt + (size_t)(n0 + rB0) * K + sc;

  auto stA = [&](int kt, int h) {
    unsigned char* dst = smem[kt & 1] + h * 16384;
    const unsigned short* s = Abase + (size_t)(h * 64) * K + kt * 64;
    GLDS16(s, dst + tid * 16);
    GLDS16(s + (size_t)128 * K, dst + (512 + tid) * 16);
  };
  auto stB = [&](int kt, int h) {
    unsigned char* dst = smem[kt & 1] + 32768 + h * 16384;
    const unsigned short* s = Bbase + (size_t)(h * 32) * K + kt * 64;
    GLDS16(s, dst + tid * 16);
    GLDS16(s + (size_t)128 * K, dst + (512 + tid) * 16);
  };
  auto stB2 = [&](int kt) {
    unsigned char* dst = smem[kt & 1] + 32768;
    const unsigned short* s = Bbase + kt * 64;
    GLDS16(s, dst + tid * 16);
    GLDS16(s + (size_t)64 * K, dst + (512 + tid) * 16);
  };

  const int aRow = (wr * 64 + lr) * 128;
  const int bRow = (wc * 32 + lr) * 128;
  const int axr = lr & 7;
#define RDA(BUF, M, KK)                                                        \
  (*(const bf16x8*)((BUF) + ((M) >> 2) * 16384 + aRow + ((M) & 3) * 2048 +     \
                    ((((KK) * 4 + lg) ^ axr) << 4)))
#define RDB(BUF, NN, KK)                                                       \
  (*(const bf16x8*)((BUF) + 32768 + ((NN) >> 1) * 16384 + bRow +               \
                    ((NN) & 1) * 2048 + ((((KK) * 4 + lg) ^ axr) << 4)))

  f32x4 acc[8][NF] = {};

  if constexpr (BN == 256) {
    bf16x8 alo[4][2], ahi[4][2], bq0[2][2], bq1[2][2];
    stA(0, 0); stB(0, 0); stB(0, 1); stA(0, 1);
    stA(1, 0); stB(1, 0); stB(1, 1);
    asm volatile("s_waitcnt vmcnt(6)" ::: "memory");
    __builtin_amdgcn_s_barrier();

#define MMQ(MB, NB, AQ, BQ)                                                    \
  _Pragma("unroll") for (int kk = 0; kk < 2; kk++)                             \
    _Pragma("unroll") for (int m = 0; m < 4; m++)                              \
      _Pragma("unroll") for (int n = 0; n < 2; n++)                            \
          acc[(MB) + m][(NB) + n] = __builtin_amdgcn_mfma_f32_16x16x32_bf16(   \
              AQ[m][kk], BQ[n][kk], acc[(MB) + m][(NB) + n], 0, 0, 0);

#define KTQ(KT, ST1, ST2, W2V, HASW2, W4V, HASW4)                              \
  {                                                                            \
    const unsigned char* buf = smem[(KT) & 1];                                 \
    /* Q1: ALL reads (aLO8, bLO4, bHI4, aHI8); stage A1(kt+1); lgkm(12) */     \
    _Pragma("unroll") for (int m = 0; m < 4; m++)                              \
      _Pragma("unroll") for (int kk = 0; kk < 2; kk++)                         \
          alo[m][kk] = RDA(buf, m, kk);                                        \
    _Pragma("unroll") for (int n = 0; n < 2; n++)                              \
      _Pragma("unroll") for (int kk = 0; kk < 2; kk++)                         \
          bq0[n][kk] = RDB(buf, n, kk);                                        \
    _Pragma("unroll") for (int n = 0; n < 2; n++)                              \
      _Pragma("unroll") for (int kk = 0; kk < 2; kk++)                         \
          bq1[n][kk] = RDB(buf, n + 2, kk);                                    \
    _Pragma("unroll") for (int m = 0; m < 4; m++)                              \
      _Pragma("unroll") for (int kk = 0; kk < 2; kk++)                         \
          ahi[m][kk] = RDA(buf, m + 4, kk);                                    \
    if (ST1) stA((KT) + 1, 1);                                                 \
    asm volatile("s_waitcnt lgkmcnt(12)" ::: "memory");                        \
    __builtin_amdgcn_sched_barrier(0);                                         \
    __builtin_amdgcn_s_setprio(1);                                             \
    MMQ(0, 0, alo, bq0)                                                        \
    __builtin_amdgcn_s_setprio(0);                                             \
    __builtin_amdgcn_s_barrier();                                              \
    /* Q2: bHI ready at lgkm(8); stage A0(kt+2); vmcnt */                      \
    if (ST2) stA((KT) + 2, 0);                                                 \
    asm volatile("s_waitcnt lgkmcnt(8)" ::: "memory");                         \
    __builtin_amdgcn_sched_barrier(0);                                         \
    __builtin_amdgcn_s_setprio(1);                                             \
    MMQ(0, 2, alo, bq1)                                                        \
    __builtin_amdgcn_s_setprio(0);                                             \
    if (HASW2) asm volatile("s_waitcnt vmcnt(%0)" ::"i"(W2V) : "memory");      \
    __builtin_amdgcn_s_barrier();                                              \
    /* Q3: aHI ready at lgkm(0); stage B0(kt+2) */                             \
    if (ST2) stB((KT) + 2, 0);                                                 \
    asm volatile("s_waitcnt lgkmcnt(0)" ::: "memory");                         \
    __builtin_amdgcn_sched_barrier(0);                                         \
    __builtin_amdgcn_s_setprio(1);                                             \
    MMQ(4, 2, ahi, bq1)                                                        \
    __builtin_amdgcn_s_setprio(0);                                             \
    __builtin_amdgcn_s_barrier();                                              \
    /* Q4: stage B1(kt+2); MFMA (operands resident); vmcnt */                  \
    if (ST2) stB((KT) + 2, 1);                                                 \
    __builtin_amdgcn_s_setprio(1);                                             \
    MMQ(4, 0, ahi, bq0)                                                        \
    __builtin_amdgcn_s_setprio(0);                                             \
    if (HASW4) asm volatile("s_waitcnt vmcnt(%0)" ::"i"(W4V) : "memory");      \
    __builtin_amdgcn_s_barrier();                                              \
  }

    for (int kt = 0; kt < nkt - 2; kt++) KTQ(kt, 1, 1, 6, 1, 6, 1);
    KTQ(nkt - 2, 1, 0, 4, 1, 0, 1);
    KTQ(nkt - 1, 0, 0, 0, 0, 0, 0);
#undef KTQ
#undef MMQ
  } else {
    bf16x8 alo[4][2], ahi[4][2], bq[2][2];
    stA(0, 0); stB2(0); stA(0, 1); stA(1, 0); stB2(1);
    asm volatile("s_waitcnt vmcnt(4)" ::: "memory");
    __builtin_amdgcn_s_barrier();

#define MM2(MB, AQ)                                                            \
  _Pragma("unroll") for (int kk = 0; kk < 2; kk++)                             \
    _Pragma("unroll") for (int m = 0; m < 4; m++)                              \
      _Pragma("unroll") for (int n = 0; n < 2; n++)                            \
          acc[(MB) + m][n] = __builtin_amdgcn_mfma_f32_16x16x32_bf16(          \
              AQ[m][kk], bq[n][kk], acc[(MB) + m][n], 0, 0, 0);

#define KT2(KT, ST1, ST2, HASW, WV)                                            \
  {                                                                            \
    const unsigned char* buf = smem[(KT) & 1];                                 \
    _Pragma("unroll") for (int m = 0; m < 4; m++)                              \
      _Pragma("unroll") for (int kk = 0; kk < 2; kk++)                         \
          alo[m][kk] = RDA(buf, m, kk);                                        \
    _Pragma("unroll") for (int n = 0; n < 2; n++)                              \
      _Pragma("unroll") for (int kk = 0; kk < 2; kk++)                         \
          bq[n][kk] = RDB(buf, n, kk);                                         \
    _Pragma("unroll") for (int m = 0; m < 4; m++)                              \
      _Pragma("unroll") for (int kk = 0; kk < 2; kk++)                         \
          ahi[m][kk] = RDA(buf, m + 4, kk);                                    \
    if (ST1) stA((KT) + 1, 1);                                                 \
    asm volatile("s_waitcnt lgkmcnt(8)" ::: "memory");                         \
    __builtin_amdgcn_sched_barrier(0);                                         \
    __builtin_amdgcn_s_setprio(1);                                             \
    MM2(0, alo)                                                                \
    __builtin_amdgcn_s_setprio(0);                                             \
    __builtin_amdgcn_s_barrier();                                              \
    if (ST2) { stA((KT) + 2, 0); stB2((KT) + 2); }                             \
    asm volatile("s_waitcnt lgkmcnt(0)" ::: "memory");                         \
    __builtin_amdgcn_sched_barrier(0);                                         \
    __builtin_amdgcn_s_setprio(1);                                             \
    MM2(4, ahi)                                                                \
    __builtin_amdgcn_s_setprio(0);                                             \
    if (HASW) asm volatile("s_waitcnt vmcnt(%0)" ::"i"(WV) : "memory");        \
    __builtin_amdgcn_s_barrier();                                              \
  }

    for (int kt = 0; kt < nkt - 2; kt++) KT2(kt, 1, 1, 1, 4);
    KT2(nkt - 2, 1, 0, 1, 0);
    KT2(nkt - 1, 0, 0, 0, 0);
#undef KT2
#undef MM2
  }
#undef RDA
#undef RDB

  const int rbase = wr * 128 + lg * 4;
  const int cbase = wc * (BN / 4) + lr;
  if constexpr (EPI == 0) {
#pragma unroll
    for (int m = 0; m < 8; m++)
#pragma unroll
      for (int n = 0; n < NF; n++)
#pragma unroll
        for (int j = 0; j < 4; j++)
          outB[(size_t)(m0 + rbase + m * 16 + j) * N + n0 + cbase + n * 16] =
              f2bf(acc[m][n][j]);
  } else if constexpr (EPI == 1) {
#pragma unroll
    for (int m = 0; m < 8; m++)
#pragma unroll
      for (int n = 0; n < NF; n++)
#pragma unroll
        for (int j = 0; j < 4; j++) {
          size_t o = (size_t)(m0 + rbase + m * 16 + j) * N + n0 + cbase + n * 16;
          outF[o] = res[o] + acc[m][n][j];
        }
  } else if constexpr (EPI == 2) {
    float* gl = (float*)smem;
    const int ab = n0 >> 1;
    __syncthreads();
#pragma unroll
    for (int half = 0; half < 2; half++) {
      if (wr == half && wc < 2) {
#pragma unroll
        for (int m = 0; m < 8; m++)
#pragma unroll
          for (int n = 0; n < NF; n++)
#pragma unroll
            for (int j = 0; j < 4; j++)
              gl[(m * 16 + lg * 4 + j) * 128 + wc * 64 + n * 16 + lr] = acc[m][n][j];
      }
      __syncthreads();
      if (wr == half && wc >= 2) {
#pragma unroll
        for (int m = 0; m < 8; m++)
#pragma unroll
          for (int n = 0; n < NF; n++)
#pragma unroll
            for (int j = 0; j < 4; j++) {
              int rl = m * 16 + lg * 4 + j;
              int cl = (wc - 2) * 64 + n * 16 + lr;
              float g = gl[rl * 128 + cl];
              float s = g / (1.0f + __expf(-g));
              outB[(size_t)(m0 + half * 128 + rl) * FF_ + ab + cl] = f2bf(s * acc[m][n][j]);
            }
      }
      __syncthreads();
    }
  } else {
    if (nt >= 12) {
#pragma unroll
      for (int m = 0; m < 8; m++)
#pragma unroll
        for (int n = 0; n < NF; n++)
#pragma unroll
          for (int j = 0; j < 4; j++)
            outB[(size_t)(m0 + rbase + m * 16 + j) * N + n0 + cbase + n * 16] =
                f2bf(acc[m][n][j]);
    } else {
      float* gl = (float*)smem;           // [2][16][256] f32 = 32KB
      const float qs = (nt < 8) ? QK_SCALE_L2E : 1.0f;
      __syncthreads();
      for (int m = 0; m < 8; m++) {
#pragma unroll
        for (int n = 0; n < NF; n++)
#pragma unroll
          for (int j = 0; j < 4; j++)
            gl[wr * 4096 + (lg * 4 + j) * 256 + wc * 64 + n * 16 + lr] = acc[m][n][j];
        __syncthreads();
#pragma unroll
        for (int n = 0; n < NF; n++)
#pragma unroll
          for (int j = 0; j < 4; j++) {
            int c = wc * 64 + n * 16 + lr;
            int d = c & 127;
            int row = m0 + wr * 128 + m * 16 + lg * 4 + j;
            int s = row & (SEQ - 1);
            float own = acc[m][n][j];
            float prt = gl[wr * 4096 + (lg * 4 + j) * 256 + (c ^ 64)];
            float cv = cosT[s * HD + d], sv = sinT[s * HD + d];
            float rot = own * cv + ((d & 64) ? prt : -prt) * sv;
            outB[(size_t)row * N + n0 + c] = f2bf(rot * qs);
          }
        __syncthreads();
      }
    }
  }
}

// ---------------- causal GQA flash attention, 32x32 swapped-QK structure --------------
// r15 load balance: bid<256 -> qtiles 15..8, bid>=256 -> qtiles 0..7 ascending, so a
// CU's round-robin pair (bid, bid+256) sums to constant 36 kv-tile-steps (was 48 max).
__global__ __launch_bounds__(256) void k_attn2(const unsigned short* __restrict__ qkv,
                                               unsigned short* __restrict__ out) {
  __shared__ __attribute__((aligned(16))) unsigned short lK[2][64 * 128];
  __shared__ __attribute__((aligned(16))) unsigned short lV[2][128 * 64];
  const float NEG = -3.0e38f;
  int bx = blockIdx.x;
  int qtile, hb;
  if (bx < 256) { qtile = 15 - (bx >> 5); hb = bx & 31; }
  else          { int b2 = bx - 256; qtile = b2 >> 5; hb = b2 & 31; }
  int h = hb & 15, b = hb >> 4;
  int q0 = qtile * 128;
  int tid = threadIdx.x, w = tid >> 6, l = tid & 63;
  int l31 = l & 31, half2 = l >> 5;
  const unsigned short* base = qkv + (size_t)b * SEQ * 4096;
  const unsigned short* Kp = base + 2048 + (h >> 1) * HD;
  const unsigned short* Vp = base + 3072 + (h >> 1) * HD;
  const int qw = q0 + w * 32;

  bf16x8 qf[8];
  {
    const unsigned short* qrow = base + (size_t)(qw + l31) * 4096 + h * HD + half2 * 8;
#pragma unroll
    for (int d = 0; d < 8; d++) qf[d] = *(const bf16x8*)(qrow + d * 16);
  }

  f32x16 oacc[4] = {};
  float mrow = NEG, lsum = 0.0f;

  const int vp = tid & 31, vdc = tid >> 5;
  u16x8 va0, va1, vb0, vb1;

  auto stageK = [&](int t) {
    unsigned char* dst = (unsigned char*)lK[t & 1];
#pragma unroll
    for (int i = 0; i < 4; i++) {
      int c = i * 256 + tid;
      int row = c >> 4;
      int g = (c & 15) ^ (row & 7);
      GLDS16(Kp + (size_t)(t * 64 + row) * 4096 + g * 8, dst + (i * 256 + w * 64) * 16);
    }
  };
  auto loadV = [&](int t) {
    const unsigned short* vr = Vp + (size_t)(t * 64 + vp * 2) * 4096 + vdc * 16;
    va0 = *(const u16x8*)(vr);
    va1 = *(const u16x8*)(vr + 8);
    vb0 = *(const u16x8*)(vr + 4096);
    vb1 = *(const u16x8*)(vr + 4096 + 8);
  };

  const int nt = (q0 >> 6) + 2;
  stageK(0);
  loadV(0);

  for (int t = 0; t < nt; t++) {
    __syncthreads();
    {
      unsigned char* lv = (unsigned char*)lV[t & 1];
#pragma unroll
      for (int j = 0; j < 16; j++) {
        int dd = vdc * 16 + j;
        unsigned short lo = (j < 8) ? va0[j] : va1[j - 8];
        unsigned short hi = (j < 8) ? vb0[j] : vb1[j - 8];
        unsigned int pkv = (unsigned int)lo | ((unsigned int)hi << 16);
        *(unsigned int*)(lv + dd * 128 + (((vp >> 2) ^ (dd & 7)) * 16) + (vp & 3) * 4) = pkv;
      }
    }
    __syncthreads();
    if (t + 1 < nt) { stageK(t + 1); loadV(t + 1); }
    const int kv0 = t * 64;
    if (kv0 <= qw + 31) {
      f32x16 sc[2] = {};
      const unsigned char* lk = (const unsigned char*)lK[t & 1];
#pragma unroll
      for (int hh = 0; hh < 2; hh++) {
        int kk = hh * 32 + l31;
        const unsigned char* krow = lk + kk * 256;
#pragma unroll
        for (int d = 0; d < 8; d++) {
          bf16x8 kf = *(const bf16x8*)(krow + (((d * 2 + half2) ^ (kk & 7)) * 16));
          sc[hh] = __builtin_amdgcn_mfma_f32_32x32x16_bf16(kf, qf[d], sc[hh], 0, 0, 0);
        }
      }
      const int qa = qw + l31;
      if (kv0 + 63 > qw) {
#pragma unroll
        for (int hh = 0; hh < 2; hh++)
#pragma unroll
          for (int r = 0; r < 16; r++) {
            int kva = kv0 + hh * 32 + (r & 3) + 8 * (r >> 2) + 4 * half2;
            if (kva > qa) sc[hh][r] = NEG;
          }
      }
      float m0v = fmaxf(sc[0][0], sc[0][1]);
      m0v = max3f(m0v, sc[0][2], sc[0][3]);
      m0v = max3f(m0v, sc[0][4], sc[0][5]);
      m0v = max3f(m0v, sc[0][6], sc[0][7]);
      m0v = max3f(m0v, sc[0][8], sc[0][9]);
      m0v = max3f(m0v, sc[0][10], sc[0][11]);
      m0v = max3f(m0v, sc[0][12], sc[0][13]);
      m0v = max3f(m0v, sc[0][14], sc[0][15]);
      float m1v = fmaxf(sc[1][0], sc[1][1]);
      m1v = max3f(m1v, sc[1][2], sc[1][3]);
      m1v = max3f(m1v, sc[1][4], sc[1][5]);
      m1v = max3f(m1v, sc[1][6], sc[1][7]);
      m1v = max3f(m1v, sc[1][8], sc[1][9]);
      m1v = max3f(m1v, sc[1][10], sc[1][11]);
      m1v = max3f(m1v, sc[1][12], sc[1][13]);
      m1v = max3f(m1v, sc[1][14], sc[1][15]);
      float mx = fmaxf(m0v, m1v);
      mx = fmaxf(mx, __shfl_xor(mx, 32));
      bool ok = (mx <= mrow + 11.0f);
      if (__ballot(ok) != ~0ull) {
        float mnew = fmaxf(mrow, mx);
        float fct = fexp2(mrow - mnew);
        mrow = mnew;
        lsum *= fct;
#pragma unroll
        for (int r = 0; r < 16; r++) {
          int rr = (r & 3) + 8 * (r >> 2) + 4 * half2;
          float fr = __shfl(fct, rr);
#pragma unroll
          for (int d = 0; d < 4; d++) oacc[d][r] *= fr;
        }
      }
      float ps = 0.0f;
#pragma unroll
      for (int hh = 0; hh < 2; hh++)
#pragma unroll
        for (int r = 0; r < 16; r++) {
          float e = fexp2(sc[hh][r] - mrow);
          sc[hh][r] = e;
          ps += e;
        }
      ps += __shfl_xor(ps, 32);
      lsum += ps;
      const unsigned char* lv = (const unsigned char*)lV[t & 1];
#pragma unroll
      for (int s = 0; s < 4; s++) {
        const int hh = s >> 1;
        const int r0 = (s & 1) * 8;
        unsigned int lo0, lo1, hi0, hi1;
        if (hh == 0) {
          lo0 = pk2(sc[0][r0 + 0], sc[0][r0 + 1]); lo1 = pk2(sc[0][r0 + 2], sc[0][r0 + 3]);
          hi0 = pk2(sc[0][r0 + 4], sc[0][r0 + 5]); hi1 = pk2(sc[0][r0 + 6], sc[0][r0 + 7]);
        } else {
          lo0 = pk2(sc[1][r0 + 0], sc[1][r0 + 1]); lo1 = pk2(sc[1][r0 + 2], sc[1][r0 + 3]);
          hi0 = pk2(sc[1][r0 + 4], sc[1][r0 + 5]); hi1 = pk2(sc[1][r0 + 6], sc[1][r0 + 7]);
        }
        unsigned int s0 = half2 ? lo0 : hi0, s1 = half2 ? lo1 : hi1;
        unsigned int rc0 = (unsigned int)__shfl_xor((int)s0, 32);
        unsigned int rc1 = (unsigned int)__shfl_xor((int)s1, 32);
        u32x4 fr;
        fr[0] = half2 ? rc0 : lo0; fr[1] = half2 ? rc1 : lo1;
        fr[2] = half2 ? hi0 : rc0; fr[3] = half2 ? hi1 : rc1;
        bf16x8 pa = __builtin_bit_cast(bf16x8, fr);
#pragma unroll
        for (int d = 0; d < 4; d++) {
          int dd = d * 32 + l31;
          bf16x8 vf = *(const bf16x8*)(lv + dd * 128 + (((s * 2 + half2) ^ (dd & 7)) * 16));
          oacc[d] = __builtin_amdgcn_mfma_f32_32x32x16_bf16(pa, vf, oacc[d], 0, 0, 0);
        }
      }
    }
  }
  float inv = 1.0f / lsum;
#pragma unroll
  for (int r = 0; r < 16; r++) {
    int rr = (r & 3) + 8 * (r >> 2) + 4 * half2;
    float ir = __shfl(inv, rr);
    size_t ob = ((size_t)(b * SEQ + qw + rr)) * 2048 + h * HD;
#pragma unroll
    for (int d = 0; d < 4; d++)
      out[ob + d * 32 + l31] = f2bf(oacc[d][r] * ir);
  }
}

// ---------------- launcher -------------------------------------------------------------
extern "C" void kernel_launch(void* const* d_in, const int* in_sizes, int n_in,
                              void* d_out, int out_size, void* d_ws, size_t ws_size,
                              hipStream_t stream) {
  const float* x = (const float*)d_in[0];
  const float* cosT = (const float*)d_in[1];
  const float* sinT = (const float*)d_in[2];
  const float* wq = (const float*)d_in[3];
  const float* wk = (const float*)d_in[4];
  const float* wv = (const float*)d_in[5];
  const float* wo = (const float*)d_in[6];
  const float* wg = (const float*)d_in[7];
  const float* wu = (const float*)d_in[8];
  const float* wd = (const float*)d_in[9];
  const float* g1 = (const float*)d_in[10];
  const float* g2 = (const float*)d_in[11];
  float* out = (float*)d_out;
  char* ws = (char*)d_ws;

  unsigned short* wqkv = (unsigned short*)(ws + 0);
  unsigned short* hbuf = (unsigned short*)(ws + 16777216);
  unsigned short* qkv = (unsigned short*)(ws + 33554432);
  unsigned short* attn_o = (unsigned short*)(ws + 67108864);
  unsigned short* wo_bf = (unsigned short*)(ws + 83886080);
  unsigned short* wgu = (unsigned short*)(ws + 33554432);
  unsigned short* act = (unsigned short*)(ws + 92274688);
  unsigned short* wdown = (unsigned short*)(ws + 0);   // overlaps hbuf: convert LATE

  // ---- attention sub-block ----
  k_prep<<<10240, 256, 0, stream>>>(wq, wk, wv, wo, wqkv, wo_bf, x, g1, hbuf);
  k_gemm8p<256, 3><<<256, 512, 0, stream>>>(hbuf, wqkv, qkv, nullptr, nullptr,
                                            4096, 2048, cosT, sinT);
  k_attn2<<<512, 256, 0, stream>>>(qkv, attn_o);
  k_gemm8p<128, 1><<<256, 512, 0, stream>>>(attn_o, wo_bf, nullptr, out, x,
                                            2048, 2048, nullptr, nullptr);
  // ---- SwiGLU MLP sub-block ----
  k_rmsnorm<<<4096, 256, 0, stream>>>(out, g2, hbuf);
  k_conv_gu<<<11008, 256, 0, stream>>>(wg, wu, wgu);
  k_gemm8p<256, 2><<<688, 512, 0, stream>>>(hbuf, wgu, act, nullptr, nullptr,
                                            11008, 2048, nullptr, nullptr);
  k_conv<<<5504, 256, 0, stream>>>(wd, wdown);   // after gateup (hbuf's last consumer)
  k_gemm8p<128, 1><<<256, 512, 0, stream>>>(act, wdown, nullptr, out, out,
                                            2048, 5504, nullptr, nullptr);
}

// Round 16
// 560.429 us; speedup vs baseline: 1.0453x; 1.0453x over previous
//
#include <hip/hip_runtime.h>

// LLM block: B=2,S=2048,D=2048,H=16,KVH=8,HD=128,FF=5504, f32 in/out, bf16 MFMA compute.
// Workspace lifetime note (r13 lesson): wdown @ ws+0 spans 22.5MB and OVERLAPS hbuf
// [16.7MB,22.5MB) -> wd MUST be converted AFTER gateup GEMM (hbuf's last consumer).
// r15 lessons: Q1-batched ds_reads (+32 VGPR) and attn anti-LPT remap both regress —
// this file is the r14 configuration (best verified: 563.7us).
#define DM 2048
#define SEQ 2048
#define HD 128
#define FF_ 5504
#define QK_SCALE_L2E 0.12751744f   // 1/sqrt(128) * log2(e); attn softmax in exp2 domain

typedef __bf16 bf16x8 __attribute__((ext_vector_type(8)));
typedef float f32x4 __attribute__((ext_vector_type(4)));
typedef float f32x16 __attribute__((ext_vector_type(16)));
typedef unsigned short u16x8 __attribute__((ext_vector_type(8)));
typedef unsigned int u32x4 __attribute__((ext_vector_type(4)));

typedef __attribute__((address_space(1))) void* gas1;
typedef __attribute__((address_space(3))) void* las3;
#define GLDS16(g, s) __builtin_amdgcn_global_load_lds((gas1)(g), (las3)(s), 16, 0, 0)

static __device__ __forceinline__ float bf2f(unsigned short u) {
  union { unsigned int i; float f; } c; c.i = ((unsigned int)u) << 16; return c.f;
}
static __device__ __forceinline__ unsigned short f2bf(float f) {
  __bf16 b = (__bf16)f;
  return __builtin_bit_cast(unsigned short, b);
}
static __device__ __forceinline__ unsigned int pk2(float a, float b) {
  return (unsigned int)f2bf(a) | ((unsigned int)f2bf(b) << 16);
}
static __device__ __forceinline__ float fexp2(float x) { return exp2f(x); }
static __device__ __forceinline__ float max3f(float a, float b, float c) {
  return fmaxf(fmaxf(a, b), c);   // clang fuses to v_max3_f32 (T17)
}

// -------- merged prep: f32->bf16 convert (wq|wk|wv|wo) + RMSNorm(x,g1) --------------
__global__ __launch_bounds__(256) void k_prep(const float* __restrict__ wq,
                                              const float* __restrict__ wk,
                                              const float* __restrict__ wv,
                                              const float* __restrict__ wo,
                                              unsigned short* __restrict__ wqkv,
                                              unsigned short* __restrict__ wo_bf,
                                              const float* __restrict__ x,
                                              const float* __restrict__ g1,
                                              unsigned short* __restrict__ hbuf) {
  int b = blockIdx.x, tid = threadIdx.x;
  if (b < 6144) {   // weight convert, 1 row/block
    const float* src;
    unsigned short* dst;
    if (b < 2048)      { src = wq + (size_t)b * DM;          dst = wqkv + (size_t)b * DM; }
    else if (b < 3072) { src = wk + (size_t)(b - 2048) * DM; dst = wqkv + 4194304 + (size_t)(b - 2048) * DM; }
    else if (b < 4096) { src = wv + (size_t)(b - 3072) * DM; dst = wqkv + 6291456 + (size_t)(b - 3072) * DM; }
    else               { src = wo + (size_t)(b - 4096) * DM; dst = wo_bf + (size_t)(b - 4096) * DM; }
    int i = tid * 8;
    float4 a = *(const float4*)&src[i];
    float4 c = *(const float4*)&src[i + 4];
    u16x8 o;
    o[0] = f2bf(a.x); o[1] = f2bf(a.y); o[2] = f2bf(a.z); o[3] = f2bf(a.w);
    o[4] = f2bf(c.x); o[5] = f2bf(c.y); o[6] = f2bf(c.z); o[7] = f2bf(c.w);
    *(u16x8*)&dst[i] = o;
  } else {          // rmsnorm, 1 row/block
    int row = b - 6144;
    const float* xr = x + (size_t)row * DM;
    float4 a = *(const float4*)&xr[tid * 8];
    float4 c = *(const float4*)&xr[tid * 8 + 4];
    float ss = a.x * a.x + a.y * a.y + a.z * a.z + a.w * a.w +
               c.x * c.x + c.y * c.y + c.z * c.z + c.w * c.w;
#pragma unroll
    for (int off = 32; off > 0; off >>= 1) ss += __shfl_xor(ss, off, 64);
    __shared__ float red[4];
    if ((tid & 63) == 0) red[tid >> 6] = ss;
    __syncthreads();
    float rs = rsqrtf((red[0] + red[1] + red[2] + red[3]) * (1.0f / DM) + 1e-5f);
    float4 ga = *(const float4*)&g1[tid * 8];
    float4 gb = *(const float4*)&g1[tid * 8 + 4];
    u16x8 o;
    o[0] = f2bf(a.x * rs * ga.x); o[1] = f2bf(a.y * rs * ga.y);
    o[2] = f2bf(a.z * rs * ga.z); o[3] = f2bf(a.w * rs * ga.w);
    o[4] = f2bf(c.x * rs * gb.x); o[5] = f2bf(c.y * rs * gb.y);
    o[6] = f2bf(c.z * rs * gb.z); o[7] = f2bf(c.w * rs * gb.w);
    *(u16x8*)&hbuf[(size_t)row * DM + tid * 8] = o;
  }
}

// ---- gate/up interleaved convert: dst row r of group t: r<128 -> wg, else wu ----
__global__ __launch_bounds__(256) void k_conv_gu(const float* __restrict__ g,
                                                 const float* __restrict__ u,
                                                 unsigned short* __restrict__ dst) {
  int i = blockIdx.x * 256 + threadIdx.x;
  int row = i >> 8;
  int c8 = (i & 255) * 8;
  int t = row >> 8, r = row & 255;
  const float* src = (r < 128) ? (g + (size_t)(t * 128 + r) * DM + c8)
                               : (u + (size_t)(t * 128 + (r - 128)) * DM + c8);
  float4 a = *(const float4*)src;
  float4 b = *(const float4*)(src + 4);
  u16x8 o;
  o[0] = f2bf(a.x); o[1] = f2bf(a.y); o[2] = f2bf(a.z); o[3] = f2bf(a.w);
  o[4] = f2bf(b.x); o[5] = f2bf(b.y); o[6] = f2bf(b.z); o[7] = f2bf(b.w);
  *(u16x8*)&dst[(size_t)row * DM + c8] = o;
}

// ---------------- plain convert (wd — MUST run after gateup GEMM, see top note) ------
__global__ __launch_bounds__(256) void k_conv(const float* __restrict__ src,
                                              unsigned short* __restrict__ dst) {
  size_t i = (size_t)(blockIdx.x * 256 + threadIdx.x) * 8;
  float4 a = *(const float4*)&src[i];
  float4 b = *(const float4*)&src[i + 4];
  u16x8 o;
  o[0] = f2bf(a.x); o[1] = f2bf(a.y); o[2] = f2bf(a.z); o[3] = f2bf(a.w);
  o[4] = f2bf(b.x); o[5] = f2bf(b.y); o[6] = f2bf(b.z); o[7] = f2bf(b.w);
  *(u16x8*)&dst[i] = o;
}

// ---------------- RMSNorm (x1, g2): one block per row ----------------
__global__ __launch_bounds__(256) void k_rmsnorm(const float* __restrict__ x,
                                                 const float* __restrict__ g,
                                                 unsigned short* __restrict__ out) {
  int row = blockIdx.x, tid = threadIdx.x;
  const float* xr = x + (size_t)row * DM;
  float4 a = *(const float4*)&xr[tid * 8];
  float4 b = *(const float4*)&xr[tid * 8 + 4];
  float ss = a.x * a.x + a.y * a.y + a.z * a.z + a.w * a.w +
             b.x * b.x + b.y * b.y + b.z * b.z + b.w * b.w;
#pragma unroll
  for (int off = 32; off > 0; off >>= 1) ss += __shfl_xor(ss, off, 64);
  __shared__ float red[4];
  if ((tid & 63) == 0) red[tid >> 6] = ss;
  __syncthreads();
  float rs = rsqrtf((red[0] + red[1] + red[2] + red[3]) * (1.0f / DM) + 1e-5f);
  float4 ga = *(const float4*)&g[tid * 8];
  float4 gb = *(const float4*)&g[tid * 8 + 4];
  u16x8 o;
  o[0] = f2bf(a.x * rs * ga.x); o[1] = f2bf(a.y * rs * ga.y);
  o[2] = f2bf(a.z * rs * ga.z); o[3] = f2bf(a.w * rs * ga.w);
  o[4] = f2bf(b.x * rs * gb.x); o[5] = f2bf(b.y * rs * gb.y);
  o[6] = f2bf(b.z * rs * gb.z); o[7] = f2bf(b.w * rs * gb.w);
  *(u16x8*)&out[(size_t)row * DM + tid * 8] = o;
}

// ============ counted-lgkm pipelined GEMM (r11-r14): C[M,N] = A[M,K]*Bt[N,K]^T ========
// BM=256, BK=64, 512 thr (8 waves 2Mx4N), 2-K-tile LDS dbuf, identity bid->tile.
// kk-OUTER MFMA ordering. Sync structure r12-verified.
// Swizzle: 16B-granule ^= (row&7); source pre-swizzled (rule #21).
// EPI: 0 bf16; 1 f32 res-add; 2 gateup-silu; 3 qkv+fused RoPE.
template <int BN, int EPI>
__global__ __launch_bounds__(512, 1) void k_gemm8p(
    const unsigned short* __restrict__ A, const unsigned short* __restrict__ Bt,
    unsigned short* __restrict__ outB, float* __restrict__ outF,
    const float* __restrict__ res, int N, int K,
    const float* __restrict__ cosT, const float* __restrict__ sinT) {
  constexpr int NF = BN / 64;
  constexpr int BUFSZ = (BN == 256) ? 65536 : 49152;
  __shared__ __attribute__((aligned(16))) unsigned char smem[2][BUFSZ];
  const int tid = threadIdx.x, w = tid >> 6, l = tid & 63;
  const int wr = w >> 2, wc = w & 3, lr = l & 15, lg = l >> 4;
  const int bswz = blockIdx.x;
  const int mt = bswz & 15, nt = bswz >> 4;
  const int m0 = mt * 256, n0 = nt * BN;
  const int nkt = K >> 6;

  const int rA0 = tid >> 3;
  const int rB0 = (BN == 256) ? (((tid >> 8) << 6) + ((tid >> 3) & 31)) : (tid >> 3);
  const int sc = ((tid & 7) ^ ((tid >> 3) & 7)) * 8;
  const unsigned short* Abase = A + (size_t)(m0 + rA0) * K + sc;
  const unsigned short* Bbase = Bt + (size_t)(n0 + rB0) * K + sc;

  auto stA = [&](int kt, int h) {
    unsigned char* dst = smem[kt & 1] + h * 16384;
    const unsigned short* s = Abase + (size_t)(h * 64) * K + kt * 64;
    GLDS16(s, dst + tid * 16);
    GLDS16(s + (size_t)128 * K, dst + (512 + tid) * 16);
  };
  auto stB = [&](int kt, int h) {
    unsigned char* dst = smem[kt & 1] + 32768 + h * 16384;
    const unsigned short* s = Bbase + (size_t)(h * 32) * K + kt * 64;
    GLDS16(s, dst + tid * 16);
    GLDS16(s + (size_t)128 * K, dst + (512 + tid) * 16);
  };
  auto stB2 = [&](int kt) {
    unsigned char* dst = smem[kt & 1] + 32768;
    const unsigned short* s = Bbase + kt * 64;
    GLDS16(s, dst + tid * 16);
    GLDS16(s + (size_t)64 * K, dst + (512 + tid) * 16);
  };

  const int aRow = (wr * 64 + lr) * 128;
  const int bRow = (wc * 32 + lr) * 128;
  const int axr = lr & 7;
#define RDA(BUF, M, KK)                                                        \
  (*(const bf16x8*)((BUF) + ((M) >> 2) * 16384 + aRow + ((M) & 3) * 2048 +     \
                    ((((KK) * 4 + lg) ^ axr) << 4)))
#define RDB(BUF, NN, KK)                                                       \
  (*(const bf16x8*)((BUF) + 32768 + ((NN) >> 1) * 16384 + bRow +               \
                    ((NN) & 1) * 2048 + ((((KK) * 4 + lg) ^ axr) << 4)))

  f32x4 acc[8][NF] = {};

  if constexpr (BN == 256) {
    bf16x8 aq[4][2], bq0[2][2], bq1[2][2];
    stA(0, 0); stB(0, 0); stB(0, 1); stA(0, 1);
    stA(1, 0); stB(1, 0); stB(1, 1);
    asm volatile("s_waitcnt vmcnt(6)" ::: "memory");
    __builtin_amdgcn_s_barrier();

#define MMQ(MB, NB, BQ)                                                        \
  _Pragma("unroll") for (int kk = 0; kk < 2; kk++)                             \
    _Pragma("unroll") for (int m = 0; m < 4; m++)                              \
      _Pragma("unroll") for (int n = 0; n < 2; n++)                            \
          acc[(MB) + m][(NB) + n] = __builtin_amdgcn_mfma_f32_16x16x32_bf16(   \
              aq[m][kk], BQ[n][kk], acc[(MB) + m][(NB) + n], 0, 0, 0);

#define KTQ(KT, ST1, ST2, W2V, HASW2, W4V, HASW4)                              \
  {                                                                            \
    const unsigned char* buf = smem[(KT) & 1];                                 \
    _Pragma("unroll") for (int m = 0; m < 4; m++)                              \
      _Pragma("unroll") for (int kk = 0; kk < 2; kk++)                         \
          aq[m][kk] = RDA(buf, m, kk);                                         \
    _Pragma("unroll") for (int n = 0; n < 2; n++)                              \
      _Pragma("unroll") for (int kk = 0; kk < 2; kk++)                         \
          bq0[n][kk] = RDB(buf, n, kk);                                        \
    _Pragma("unroll") for (int n = 0; n < 2; n++)                              \
      _Pragma("unroll") for (int kk = 0; kk < 2; kk++)                         \
          bq1[n][kk] = RDB(buf, n + 2, kk);                                    \
    if (ST1) stA((KT) + 1, 1);                                                 \
    asm volatile("s_waitcnt lgkmcnt(4)" ::: "memory");                         \
    __builtin_amdgcn_sched_barrier(0);                                         \
    __builtin_amdgcn_s_setprio(1);                                             \
    MMQ(0, 0, bq0)                                                             \
    __builtin_amdgcn_s_setprio(0);                                             \
    __builtin_amdgcn_s_barrier();                                              \
    if (ST2) stA((KT) + 2, 0);                                                 \
    asm volatile("s_waitcnt lgkmcnt(0)" ::: "memory");                         \
    __builtin_amdgcn_sched_barrier(0);                                         \
    __builtin_amdgcn_s_setprio(1);                                             \
    MMQ(0, 2, bq1)                                                             \
    __builtin_amdgcn_s_setprio(0);                                             \
    if (HASW2) asm volatile("s_waitcnt vmcnt(%0)" ::"i"(W2V) : "memory");      \
    __builtin_amdgcn_s_barrier();                                              \
    _Pragma("unroll") for (int m = 0; m < 4; m++)                              \
      _Pragma("unroll") for (int kk = 0; kk < 2; kk++)                         \
          aq[m][kk] = RDA(buf, m + 4, kk);                                     \
    if (ST2) stB((KT) + 2, 0);                                                 \
    asm volatile("s_waitcnt lgkmcnt(0)" ::: "memory");                         \
    __builtin_amdgcn_sched_barrier(0);                                         \
    __builtin_amdgcn_s_setprio(1);                                             \
    MMQ(4, 2, bq1)                                                             \
    __builtin_amdgcn_s_setprio(0);                                             \
    __builtin_amdgcn_s_barrier();                                              \
    if (ST2) stB((KT) + 2, 1);                                                 \
    __builtin_amdgcn_s_setprio(1);                                             \
    MMQ(4, 0, bq0)                                                             \
    __builtin_amdgcn_s_setprio(0);                                             \
    if (HASW4) asm volatile("s_waitcnt vmcnt(%0)" ::"i"(W4V) : "memory");      \
    __builtin_amdgcn_s_barrier();                                              \
  }

    for (int kt = 0; kt < nkt - 2; kt++) KTQ(kt, 1, 1, 6, 1, 6, 1);
    KTQ(nkt - 2, 1, 0, 4, 1, 0, 1);
    KTQ(nkt - 1, 0, 0, 0, 0, 0, 0);
#undef KTQ
#undef MMQ
  } else {
    bf16x8 alo[4][2], ahi[4][2], bq[2][2];
    stA(0, 0); stB2(0); stA(0, 1); stA(1, 0); stB2(1);
    asm volatile("s_waitcnt vmcnt(4)" ::: "memory");
    __builtin_amdgcn_s_barrier();

#define MM2(MB, AQ)                                                            \
  _Pragma("unroll") for (int kk = 0; kk < 2; kk++)                             \
    _Pragma("unroll") for (int m = 0; m < 4; m++)                              \
      _Pragma("unroll") for (int n = 0; n < 2; n++)                            \
          acc[(MB) + m][n] = __builtin_amdgcn_mfma_f32_16x16x32_bf16(          \
              AQ[m][kk], bq[n][kk], acc[(MB) + m][n], 0, 0, 0);

#define KT2(KT, ST1, ST2, HASW, WV)                                            \
  {                                                                            \
    const unsigned char* buf = smem[(KT) & 1];                                 \
    _Pragma("unroll") for (int m = 0; m < 4; m++)                              \
      _Pragma("unroll") for (int kk = 0; kk < 2; kk++)                         \
          alo[m][kk] = RDA(buf, m, kk);                                        \
    _Pragma("unroll") for (int n = 0; n < 2; n++)                              \
      _Pragma("unroll") for (int kk = 0; kk < 2; kk++)                         \
          bq[n][kk] = RDB(buf, n, kk);                                         \
    _Pragma("unroll") for (int m = 0; m < 4; m++)                              \
      _Pragma("unroll") for (int kk = 0; kk < 2; kk++)                         \
          ahi[m][kk] = RDA(buf, m + 4, kk);                                    \
    if (ST1) stA((KT) + 1, 1);                                                 \
    asm volatile("s_waitcnt lgkmcnt(8)" ::: "memory");                         \
    __builtin_amdgcn_sched_barrier(0);                                         \
    __builtin_amdgcn_s_setprio(1);                                             \
    MM2(0, alo)                                                                \
    __builtin_amdgcn_s_setprio(0);                                             \
    __builtin_amdgcn_s_barrier();                                              \
    if (ST2) { stA((KT) + 2, 0); stB2((KT) + 2); }                             \
    asm volatile("s_waitcnt lgkmcnt(0)" ::: "memory");                         \
    __builtin_amdgcn_sched_barrier(0);                                         \
    __builtin_amdgcn_s_setprio(1);                                             \
    MM2(4, ahi)                                                                \
    __builtin_amdgcn_s_setprio(0);                                             \
    if (HASW) asm volatile("s_waitcnt vmcnt(%0)" ::"i"(WV) : "memory");        \
    __builtin_amdgcn_s_barrier();                                              \
  }

    for (int kt = 0; kt < nkt - 2; kt++) KT2(kt, 1, 1, 1, 4);
    KT2(nkt - 2, 1, 0, 1, 0);
    KT2(nkt - 1, 0, 0, 0, 0);
#undef KT2
#undef MM2
  }
#undef RDA
#undef RDB

  const int rbase = wr * 128 + lg * 4;
  const int cbase = wc * (BN / 4) + lr;
  if constexpr (EPI == 0) {
#pragma unroll
    for (int m = 0; m < 8; m++)
#pragma unroll
      for (int n = 0; n < NF; n++)
#pragma unroll
        for (int j = 0; j < 4; j++)
          outB[(size_t)(m0 + rbase + m * 16 + j) * N + n0 + cbase + n * 16] =
              f2bf(acc[m][n][j]);
  } else if constexpr (EPI == 1) {
#pragma unroll
    for (int m = 0; m < 8; m++)
#pragma unroll
      for (int n = 0; n < NF; n++)
#pragma unroll
        for (int j = 0; j < 4; j++) {
          size_t o = (size_t)(m0 + rbase + m * 16 + j) * N + n0 + cbase + n * 16;
          outF[o] = res[o] + acc[m][n][j];
        }
  } else if constexpr (EPI == 2) {
    float* gl = (float*)smem;
    const int ab = n0 >> 1;
    __syncthreads();
#pragma unroll
    for (int half = 0; half < 2; half++) {
      if (wr == half && wc < 2) {
#pragma unroll
        for (int m = 0; m < 8; m++)
#pragma unroll
          for (int n = 0; n < NF; n++)
#pragma unroll
            for (int j = 0; j < 4; j++)
              gl[(m * 16 + lg * 4 + j) * 128 + wc * 64 + n * 16 + lr] = acc[m][n][j];
      }
      __syncthreads();
      if (wr == half && wc >= 2) {
#pragma unroll
        for (int m = 0; m < 8; m++)
#pragma unroll
          for (int n = 0; n < NF; n++)
#pragma unroll
            for (int j = 0; j < 4; j++) {
              int rl = m * 16 + lg * 4 + j;
              int cl = (wc - 2) * 64 + n * 16 + lr;
              float g = gl[rl * 128 + cl];
              float s = g / (1.0f + __expf(-g));
              outB[(size_t)(m0 + half * 128 + rl) * FF_ + ab + cl] = f2bf(s * acc[m][n][j]);
            }
      }
      __syncthreads();
    }
  } else {
    if (nt >= 12) {
#pragma unroll
      for (int m = 0; m < 8; m++)
#pragma unroll
        for (int n = 0; n < NF; n++)
#pragma unroll
          for (int j = 0; j < 4; j++)
            outB[(size_t)(m0 + rbase + m * 16 + j) * N + n0 + cbase + n * 16] =
                f2bf(acc[m][n][j]);
    } else {
      float* gl = (float*)smem;           // [2][16][256] f32 = 32KB
      const float qs = (nt < 8) ? QK_SCALE_L2E : 1.0f;
      __syncthreads();
      for (int m = 0; m < 8; m++) {
#pragma unroll
        for (int n = 0; n < NF; n++)
#pragma unroll
          for (int j = 0; j < 4; j++)
            gl[wr * 4096 + (lg * 4 + j) * 256 + wc * 64 + n * 16 + lr] = acc[m][n][j];
        __syncthreads();
#pragma unroll
        for (int n = 0; n < NF; n++)
#pragma unroll
          for (int j = 0; j < 4; j++) {
            int c = wc * 64 + n * 16 + lr;
            int d = c & 127;
            int row = m0 + wr * 128 + m * 16 + lg * 4 + j;
            int s = row & (SEQ - 1);
            float own = acc[m][n][j];
            float prt = gl[wr * 4096 + (lg * 4 + j) * 256 + (c ^ 64)];
            float cv = cosT[s * HD + d], sv = sinT[s * HD + d];
            float rot = own * cv + ((d & 64) ? prt : -prt) * sv;
            outB[(size_t)row * N + n0 + c] = f2bf(rot * qs);
          }
        __syncthreads();
      }
    }
  }
}

// ---------------- causal GQA flash attention, 32x32 swapped-QK structure --------------
__global__ __launch_bounds__(256) void k_attn2(const unsigned short* __restrict__ qkv,
                                               unsigned short* __restrict__ out) {
  __shared__ __attribute__((aligned(16))) unsigned short lK[2][64 * 128];
  __shared__ __attribute__((aligned(16))) unsigned short lV[2][128 * 64];
  const float NEG = -3.0e38f;
  int bx = blockIdx.x;
  int qtile = 15 - (bx >> 5);          // LPT: heaviest q-tiles dispatched first
  int hb = bx & 31;
  int h = hb & 15, b = hb >> 4;
  int q0 = qtile * 128;
  int tid = threadIdx.x, w = tid >> 6, l = tid & 63;
  int l31 = l & 31, half2 = l >> 5;
  const unsigned short* base = qkv + (size_t)b * SEQ * 4096;
  const unsigned short* Kp = base + 2048 + (h >> 1) * HD;
  const unsigned short* Vp = base + 3072 + (h >> 1) * HD;
  const int qw = q0 + w * 32;

  bf16x8 qf[8];
  {
    const unsigned short* qrow = base + (size_t)(qw + l31) * 4096 + h * HD + half2 * 8;
#pragma unroll
    for (int d = 0; d < 8; d++) qf[d] = *(const bf16x8*)(qrow + d * 16);
  }

  f32x16 oacc[4] = {};
  float mrow = NEG, lsum = 0.0f;

  const int vp = tid & 31, vdc = tid >> 5;
  u16x8 va0, va1, vb0, vb1;

  auto stageK = [&](int t) {
    unsigned char* dst = (unsigned char*)lK[t & 1];
#pragma unroll
    for (int i = 0; i < 4; i++) {
      int c = i * 256 + tid;
      int row = c >> 4;
      int g = (c & 15) ^ (row & 7);
      GLDS16(Kp + (size_t)(t * 64 + row) * 4096 + g * 8, dst + (i * 256 + w * 64) * 16);
    }
  };
  auto loadV = [&](int t) {
    const unsigned short* vr = Vp + (size_t)(t * 64 + vp * 2) * 4096 + vdc * 16;
    va0 = *(const u16x8*)(vr);
    va1 = *(const u16x8*)(vr + 8);
    vb0 = *(const u16x8*)(vr + 4096);
    vb1 = *(const u16x8*)(vr + 4096 + 8);
  };

  const int nt = (q0 >> 6) + 2;
  stageK(0);
  loadV(0);

  for (int t = 0; t < nt; t++) {
    __syncthreads();
    {
      unsigned char* lv = (unsigned char*)lV[t & 1];
#pragma unroll
      for (int j = 0; j < 16; j++) {
        int dd = vdc * 16 + j;
        unsigned short lo = (j < 8) ? va0[j] : va1[j - 8];
        unsigned short hi = (j < 8) ? vb0[j] : vb1[j - 8];
        unsigned int pkv = (unsigned int)lo | ((unsigned int)hi << 16);
        *(unsigned int*)(lv + dd * 128 + (((vp >> 2) ^ (dd & 7)) * 16) + (vp & 3) * 4) = pkv;
      }
    }
    __syncthreads();
    if (t + 1 < nt) { stageK(t + 1); loadV(t + 1); }
    const int kv0 = t * 64;
    if (kv0 <= qw + 31) {
      f32x16 sc[2] = {};
      const unsigned char* lk = (const unsigned char*)lK[t & 1];
#pragma unroll
      for (int hh = 0; hh < 2; hh++) {
        int kk = hh * 32 + l31;
        const unsigned char* krow = lk + kk * 256;
#pragma unroll
        for (int d = 0; d < 8; d++) {
          bf16x8 kf = *(const bf16x8*)(krow + (((d * 2 + half2) ^ (kk & 7)) * 16));
          sc[hh] = __builtin_amdgcn_mfma_f32_32x32x16_bf16(kf, qf[d], sc[hh], 0, 0, 0);
        }
      }
      const int qa = qw + l31;
      if (kv0 + 63 > qw) {
#pragma unroll
        for (int hh = 0; hh < 2; hh++)
#pragma unroll
          for (int r = 0; r < 16; r++) {
            int kva = kv0 + hh * 32 + (r & 3) + 8 * (r >> 2) + 4 * half2;
            if (kva > qa) sc[hh][r] = NEG;
          }
      }
      float m0v = fmaxf(sc[0][0], sc[0][1]);
      m0v = max3f(m0v, sc[0][2], sc[0][3]);
      m0v = max3f(m0v, sc[0][4], sc[0][5]);
      m0v = max3f(m0v, sc[0][6], sc[0][7]);
      m0v = max3f(m0v, sc[0][8], sc[0][9]);
      m0v = max3f(m0v, sc[0][10], sc[0][11]);
      m0v = max3f(m0v, sc[0][12], sc[0][13]);
      m0v = max3f(m0v, sc[0][14], sc[0][15]);
      float m1v = fmaxf(sc[1][0], sc[1][1]);
      m1v = max3f(m1v, sc[1][2], sc[1][3]);
      m1v = max3f(m1v, sc[1][4], sc[1][5]);
      m1v = max3f(m1v, sc[1][6], sc[1][7]);
      m1v = max3f(m1v, sc[1][8], sc[1][9]);
      m1v = max3f(m1v, sc[1][10], sc[1][11]);
      m1v = max3f(m1v, sc[1][12], sc[1][13]);
      m1v = max3f(m1v, sc[1][14], sc[1][15]);
      float mx = fmaxf(m0v, m1v);
      mx = fmaxf(mx, __shfl_xor(mx, 32));
      bool ok = (mx <= mrow + 11.0f);
      if (__ballot(ok) != ~0ull) {
        float mnew = fmaxf(mrow, mx);
        float fct = fexp2(mrow - mnew);
        mrow = mnew;
        lsum *= fct;
#pragma unroll
        for (int r = 0; r < 16; r++) {
          int rr = (r & 3) + 8 * (r >> 2) + 4 * half2;
          float fr = __shfl(fct, rr);
#pragma unroll
          for (int d = 0; d < 4; d++) oacc[d][r] *= fr;
        }
      }
      float ps = 0.0f;
#pragma unroll
      for (int hh = 0; hh < 2; hh++)
#pragma unroll
        for (int r = 0; r < 16; r++) {
          float e = fexp2(sc[hh][r] - mrow);
          sc[hh][r] = e;
          ps += e;
        }
      ps += __shfl_xor(ps, 32);
      lsum += ps;
      const unsigned char* lv = (const unsigned char*)lV[t & 1];
#pragma unroll
      for (int s = 0; s < 4; s++) {
        const int hh = s >> 1;
        const int r0 = (s & 1) * 8;
        unsigned int lo0, lo1, hi0, hi1;
        if (hh == 0) {
          lo0 = pk2(sc[0][r0 + 0], sc[0][r0 + 1]); lo1 = pk2(sc[0][r0 + 2], sc[0][r0 + 3]);
          hi0 = pk2(sc[0][r0 + 4], sc[0][r0 + 5]); hi1 = pk2(sc[0][r0 + 6], sc[0][r0 + 7]);
        } else {
          lo0 = pk2(sc[1][r0 + 0], sc[1][r0 + 1]); lo1 = pk2(sc[1][r0 + 2], sc[1][r0 + 3]);
          hi0 = pk2(sc[1][r0 + 4], sc[1][r0 + 5]); hi1 = pk2(sc[1][r0 + 6], sc[1][r0 + 7]);
        }
        unsigned int s0 = half2 ? lo0 : hi0, s1 = half2 ? lo1 : hi1;
        unsigned int rc0 = (unsigned int)__shfl_xor((int)s0, 32);
        unsigned int rc1 = (unsigned int)__shfl_xor((int)s1, 32);
        u32x4 fr;
        fr[0] = half2 ? rc0 : lo0; fr[1] = half2 ? rc1 : lo1;
        fr[2] = half2 ? hi0 : rc0; fr[3] = half2 ? hi1 : rc1;
        bf16x8 pa = __builtin_bit_cast(bf16x8, fr);
#pragma unroll
        for (int d = 0; d < 4; d++) {
          int dd = d * 32 + l31;
          bf16x8 vf = *(const bf16x8*)(lv + dd * 128 + (((s * 2 + half2) ^ (dd & 7)) * 16));
          oacc[d] = __builtin_amdgcn_mfma_f32_32x32x16_bf16(pa, vf, oacc[d], 0, 0, 0);
        }
      }
    }
  }
  float inv = 1.0f / lsum;
#pragma unroll
  for (int r = 0; r < 16; r++) {
    int rr = (r & 3) + 8 * (r >> 2) + 4 * half2;
    float ir = __shfl(inv, rr);
    size_t ob = ((size_t)(b * SEQ + qw + rr)) * 2048 + h * HD;
#pragma unroll
    for (int d = 0; d < 4; d++)
      out[ob + d * 32 + l31] = f2bf(oacc[d][r] * ir);
  }
}

// ---------------- launcher -------------------------------------------------------------
extern "C" void kernel_launch(void* const* d_in, const int* in_sizes, int n_in,
                              void* d_out, int out_size, void* d_ws, size_t ws_size,
                              hipStream_t stream) {
  const float* x = (const float*)d_in[0];
  const float* cosT = (const float*)d_in[1];
  const float* sinT = (const float*)d_in[2];
  const float* wq = (const float*)d_in[3];
  const float* wk = (const float*)d_in[4];
  const float* wv = (const float*)d_in[5];
  const float* wo = (const float*)d_in[6];
  const float* wg = (const float*)d_in[7];
  const float* wu = (const float*)d_in[8];
  const float* wd = (const float*)d_in[9];
  const float* g1 = (const float*)d_in[10];
  const float* g2 = (const float*)d_in[11];
  float* out = (float*)d_out;
  char* ws = (char*)d_ws;

  unsigned short* wqkv = (unsigned short*)(ws + 0);
  unsigned short* hbuf = (unsigned short*)(ws + 16777216);
  unsigned short* qkv = (unsigned short*)(ws + 33554432);
  unsigned short* attn_o = (unsigned short*)(ws + 67108864);
  unsigned short* wo_bf = (unsigned short*)(ws + 83886080);
  unsigned short* wgu = (unsigned short*)(ws + 33554432);
  unsigned short* act = (unsigned short*)(ws + 92274688);
  unsigned short* wdown = (unsigned short*)(ws + 0);   // overlaps hbuf: convert LATE

  // ---- attention sub-block ----
  k_prep<<<10240, 256, 0, stream>>>(wq, wk, wv, wo, wqkv, wo_bf, x, g1, hbuf);
  k_gemm8p<256, 3><<<256, 512, 0, stream>>>(hbuf, wqkv, qkv, nullptr, nullptr,
                                            4096, 2048, cosT, sinT);
  k_attn2<<<512, 256, 0, stream>>>(qkv, attn_o);
  k_gemm8p<128, 1><<<256, 512, 0, stream>>>(attn_o, wo_bf, nullptr, out, x,
                                            2048, 2048, nullptr, nullptr);
  // ---- SwiGLU MLP sub-block ----
  k_rmsnorm<<<4096, 256, 0, stream>>>(out, g2, hbuf);
  k_conv_gu<<<11008, 256, 0, stream>>>(wg, wu, wgu);
  k_gemm8p<256, 2><<<688, 512, 0, stream>>>(hbuf, wgu, act, nullptr, nullptr,
                                            11008, 2048, nullptr, nullptr);
  k_conv<<<5504, 256, 0, stream>>>(wd, wdown);   // after gateup (hbuf's last consumer)
  k_gemm8p<128, 1><<<256, 512, 0, stream>>>(act, wdown, nullptr, out, out,
                                            2048, 5504, nullptr, nullptr);
}